// Round 6
// baseline (320.185 us; speedup 1.0000x reference)
//
#include <hip/hip_runtime.h>

typedef unsigned int uint;
typedef unsigned short ushort_t;
typedef unsigned long long u64;
typedef __attribute__((ext_vector_type(8))) short bf16x8;
typedef __attribute__((ext_vector_type(4))) float f32x4;

#define K_CODES 1024
#define DIM     256
#define NB      16
#define NT      4096
#define NROWS   65536
#define Q_SIZE  16777216
#define IDX_OFF ((size_t)Q_SIZE)
#define LOSS_OFF ((size_t)(Q_SIZE + NROWS))

// fast path geometry: 16 rows/block, 2 waves (code halves), 8 blocks/CU
#define TMQ  16
#define ASTQ 16          // Alds stride (words): 64 B rows -> lane-linear DMA staging
#define CAPQ 768
#define EPS  6e-3f

// fallback geometry (R2-proven, untouched)
#define TM   32

// fast-path ws layout: [0] loss double; [4096] e2 f32[1024]; [32768] cbf bf16 512 KB
#define WS_E2   4096
#define WS_CBF  32768
#define WS_REQ  (WS_CBF + K_CODES * DIM * 2)   // 557056

__device__ __forceinline__ ushort_t f2bf(float f) {
    uint u = __builtin_bit_cast(uint, f);
    return (ushort_t)((u + 0x7FFFu + ((u >> 16) & 1u)) >> 16);   // RNE
}

// async global->LDS DMA, 16 B per lane; lds arg must be wave-uniform base
__device__ __forceinline__ void gl2lds16(const void* g, void* l) {
    __builtin_amdgcn_global_load_lds((const __attribute__((address_space(1))) void*)g,
                                     (__attribute__((address_space(3))) void*)l,
                                     16, 0, 0);
}

// ---- numpy pairwise_sum(a*a), n=256 (bit-exact, R2-verified) ---------------
template<int S>
__device__ __forceinline__ float np_pw128_sq(const float* __restrict__ a) {
#pragma clang fp contract(off)
    float r[8];
#pragma unroll
    for (int j = 0; j < 8; ++j) { float v = a[j * S]; r[j] = v * v; }
    for (int i = 8; i < 128; i += 8) {
#pragma unroll
        for (int j = 0; j < 8; ++j) { float v = a[(i + j) * S]; r[j] += v * v; }
    }
    return ((r[0] + r[1]) + (r[2] + r[3])) + ((r[4] + r[5]) + (r[6] + r[7]));
}
template<int S>
__device__ __forceinline__ float np_sum256_sq(const float* __restrict__ a) {
#pragma clang fp contract(off)
    float s0 = np_pw128_sq<S>(a);
    float s1 = np_pw128_sq<S>(a + 128 * S);
    return s0 + s1;
}

// ============================ FAST PATH (MFMA) ==============================

// K1: e2 norms + fragment-order bf16 codebook + loss=0
// cbf part spread over 256 blocks (half-slot = 8 B per thread) for HBM-latency TLP
__global__ __launch_bounds__(256) void k_prep(const float* __restrict__ cb,
                                              float* __restrict__ e2,
                                              ushort_t* __restrict__ cbf,
                                              double* __restrict__ loss_acc) {
    int g = blockIdx.x;
    if (g < 256) {            // slot s = (tileN*8+kc)*64+lane; 16 B/slot, 2 threads/slot
        int hs   = g * 256 + threadIdx.x;          // 0..65535
        int s    = hs >> 1, part = hs & 1;
        int lane = s & 63, kc = (s >> 6) & 7, tileN = s >> 9;
        int code = tileN * 16 + (lane & 15);
        int k0   = kc * 32 + (lane >> 4) * 8 + part * 4;
        const float* p = cb + (size_t)code * DIM + k0;
        union { ushort_t u[4]; u64 v; } o;
#pragma unroll
        for (int j = 0; j < 4; ++j) o.u[j] = f2bf(p[j]);
        *(u64*)(cbf + (size_t)s * 8 + part * 4) = o.v;
    } else if (g < 260) {     // np-exact code norms
        int k = (g - 256) * 256 + threadIdx.x;
        e2[k] = np_sum256_sq<1>(cb + (size_t)k * DIM);
    } else {
        if (threadIdx.x == 0) *loss_acc = 0.0;
    }
}

// K2: 128-thread blocks (2 waves = 2 code halves), 16 rows each, 8 blocks/CU.
// Same per-(row,half-stream) screen semantics as the R2-proven kernel; exact
// np rescore unchanged -> bit-identical outputs, 2x resident waves per CU.
__global__ __launch_bounds__(128, 4) void k_main_mfma(const float* __restrict__ x,
                                                      const float* __restrict__ cb,
                                                      const float* __restrict__ e2g,
                                                      const ushort_t* __restrict__ cbf,
                                                      float* __restrict__ out,
                                                      double* __restrict__ loss_acc) {
    __shared__ __align__(16) float Alds[DIM * ASTQ];         // 16384 B  x tile [c][t]
    __shared__ __align__(16) uint  uni[CAPQ];                //  3072 B  cand U AsP
    __shared__ u64   keys[TMQ];                              //   128 B
    __shared__ float As[TMQ];                                //    64 B
    __shared__ float wred[2];
    __shared__ int   cnt;
    // total ~19.7 KiB -> 8 blocks/CU (16 waves)

    uint* const cand = uni;
    float (* const AsP)[8][2] = (float (*)[8][2])uni;        // [16][8][2] = 1024 B

    const int tid  = threadIdx.x;       // 0..127
    const int lane = tid & 63;
    const int wid  = tid >> 6;          // 0..1 = code half (tiles 0..31 / 32..63)
    const int col  = lane & 15;
    const int quad = lane >> 4;

    const int b  = blockIdx.x >> 8;
    const int t0 = (blockIdx.x & 255) * TMQ;
    const float* xb = x + (size_t)b * DIM * NT + t0;

    if (tid < TMQ) keys[tid] = ~0ull;
    if (tid == 0) cnt = 0;

    // stage x tile fp32 [c][t] via global_load_lds (lane-linear with ASTQ=16):
    // lds byte = 2048*pp + 16*tid = (2048*pp + 1024*wid) + 16*lane
    {
        int c0 = tid >> 2, t4 = (tid & 3) * 4;
#pragma unroll
        for (int pp = 0; pp < 8; ++pp)
            gl2lds16(xb + (size_t)(pp * 32 + c0) * NT + t4, &Alds[512 * pp + 256 * wid]);
    }
    __syncthreads();

    // np row-norm partials into AsP (aliases cand region; freed before K-loop)
    {
#pragma clang fp contract(off)
        int rw = tid >> 3, j = tid & 7;       // 16 rows x 8 j = 128 threads
        float rlo = 0.f, rhi = 0.f;
        for (int m = 0; m < 16; ++m)  { float v = Alds[(j + 8 * m) * ASTQ + rw];  rlo += v * v; }
        for (int m = 16; m < 32; ++m) { float v = Alds[(j + 8 * m) * ASTQ + rw];  rhi += v * v; }
        AsP[rw][j][0] = rlo; AsP[rw][j][1] = rhi;
    }

    // A fragments (rows 0..15, both waves identical): lane holds A[col][kc*32+quad*8+j]
    bf16x8 afrag[8];
#pragma unroll
    for (int kc = 0; kc < 8; ++kc) {
        union { ushort_t u[8]; bf16x8 v; } tmp;
#pragma unroll
        for (int j = 0; j < 8; ++j)
            tmp.u[j] = f2bf(Alds[(kc * 32 + quad * 8 + j) * ASTQ + col]);
        afrag[kc] = tmp.v;
    }

    __syncthreads();   // AsP complete

    if (tid < TMQ) {   // np combine lo/hi then lo+hi (bit-exact np_sum256_sq)
        const float* p = &AsP[tid][0][0];
        float lo = ((p[0] + p[2]) + (p[4] + p[6])) + ((p[8] + p[10]) + (p[12] + p[14]));
        float hi = ((p[1] + p[3]) + (p[5] + p[7])) + ((p[9] + p[11]) + (p[13] + p[15]));
        As[tid] = lo + hi;
    }
    __syncthreads();   // As done; uni region now free for cand

    // ---- barrier-free K-loop (R2-proven form), wave wid scans its half -----
    float rowmin[4] = {3.4e38f, 3.4e38f, 3.4e38f, 3.4e38f};
    float sb[16];
    const bf16x8* bp = (const bf16x8*)cbf + (size_t)(wid * 32) * 8 * 64 + lane;

    bf16x8 bfb[2][8];
    float  e2pre[2];
#pragma unroll
    for (int kc = 0; kc < 8; ++kc) bfb[0][kc] = bp[kc * 64];
    e2pre[0] = e2g[(wid * 32) * 16 + col];

#pragma unroll
    for (int it = 0; it < 32; ++it) {
        const int cur = it & 1, nxt = cur ^ 1;
        if (it < 31) {      // issue next tile's loads before consuming current
#pragma unroll
            for (int kc = 0; kc < 8; ++kc)
                bfb[nxt][kc] = bp[((it + 1) * 8 + kc) * 64];
            e2pre[nxt] = e2g[(wid * 32 + it + 1) * 16 + col];
        }
        f32x4 acc = {0.f, 0.f, 0.f, 0.f};
#pragma unroll
        for (int kc = 0; kc < 8; ++kc)
            acc = __builtin_amdgcn_mfma_f32_16x16x32_bf16(afrag[kc], bfb[cur][kc], acc, 0, 0, 0);

        float e2v = e2pre[cur];
#pragma unroll
        for (int r = 0; r < 4; ++r) sb[(it & 3) * 4 + r] = e2v - 2.0f * acc[r];

        if ((it & 3) == 3) {   // checkpoint: row-min over last 64 codes + collect
            float bm[4];
#pragma unroll
            for (int r = 0; r < 4; ++r)
                bm[r] = fminf(fminf(sb[r], sb[4 + r]), fminf(sb[8 + r], sb[12 + r]));
#pragma unroll
            for (int mask = 1; mask < 16; mask <<= 1)
#pragma unroll
                for (int r = 0; r < 4; ++r) bm[r] = fminf(bm[r], __shfl_xor(bm[r], mask, 64));
#pragma unroll
            for (int r = 0; r < 4; ++r) rowmin[r] = fminf(rowmin[r], bm[r]);
#pragma unroll
            for (int tb = 0; tb < 4; ++tb)
#pragma unroll
                for (int r = 0; r < 4; ++r)
                    if (sb[tb * 4 + r] <= rowmin[r] + EPS) {
                        int code = (wid * 32 + (it - 3 + tb)) * 16 + col;
                        int rowL = quad * 4 + r;
                        int pos  = atomicAdd(&cnt, 1);
                        if (pos < CAPQ) cand[pos] = ((uint)rowL << 10) | (uint)code;
                    }
        }
    }
    __syncthreads();   // cand/cnt all ready

    // exact np-chain rescore (identical fmaf order; crow via float4)
    {
        int n = cnt;
        bool over = (n > CAPQ);
        int total = over ? (TMQ * K_CODES) : n;
        for (int i = tid; i < total; i += 128) {
            uint pk   = over ? (uint)i : cand[i];
            int row   = pk >> 10;
            int code  = pk & 1023;
            const float4* crow4 = (const float4*)(cb + (size_t)code * DIM);
            float acc = 0.f;
#pragma unroll 4
            for (int c8 = 0; c8 < 32; ++c8) {
                float4 u = crow4[2 * c8];
                float4 v = crow4[2 * c8 + 1];
                int c0 = c8 * 8;
                acc = __builtin_fmaf(Alds[(c0 + 0) * ASTQ + row], u.x, acc);
                acc = __builtin_fmaf(Alds[(c0 + 1) * ASTQ + row], u.y, acc);
                acc = __builtin_fmaf(Alds[(c0 + 2) * ASTQ + row], u.z, acc);
                acc = __builtin_fmaf(Alds[(c0 + 3) * ASTQ + row], u.w, acc);
                acc = __builtin_fmaf(Alds[(c0 + 4) * ASTQ + row], v.x, acc);
                acc = __builtin_fmaf(Alds[(c0 + 5) * ASTQ + row], v.y, acc);
                acc = __builtin_fmaf(Alds[(c0 + 6) * ASTQ + row], v.z, acc);
                acc = __builtin_fmaf(Alds[(c0 + 7) * ASTQ + row], v.w, acc);
            }
            float t1 = As[row] - 2.0f * acc;     // fl(A-2B): 2*acc exact
            float d  = t1 + e2g[code];           // fl(+C)
            uint ub  = __builtin_bit_cast(uint, d);
            ub = (ub >> 31) ? ~ub : (ub | 0x80000000u);   // sortable float key
            atomicMin(&keys[row], ((u64)ub << 32) | (u64)(uint)code);
        }
    }
    __syncthreads();

    if (tid < TMQ) out[IDX_OFF + (size_t)blockIdx.x * TMQ + tid] =
        (float)(int)(keys[tid] & 1023u);

    // epilogue: gather q (float4), transposed coalesced write, loss partial
    float lsum = 0.f;
    {
        int tt = tid & 15;
        int cq = tid >> 4;     // 0..7 -> channel block [cq*32, cq*32+32)
        int myidx = (int)(keys[tt] & 1023u);
        const float4* myrow4 = (const float4*)(cb + (size_t)myidx * DIM + cq * 32);
        float* oq = out + (size_t)b * DIM * NT + (size_t)(cq * 32) * NT + t0 + tt;
#pragma unroll
        for (int i8 = 0; i8 < 8; ++i8) {
            float4 q4 = myrow4[i8];
            float qv[4] = { q4.x, q4.y, q4.z, q4.w };
#pragma unroll
            for (int u = 0; u < 4; ++u) {
                int c = cq * 32 + i8 * 4 + u;
                float dd = qv[u] - Alds[c * ASTQ + tt];
                lsum += dd * dd;
                oq[(size_t)(i8 * 4 + u) * NT] = qv[u];
            }
        }
    }
#pragma unroll
    for (int off = 32; off > 0; off >>= 1) lsum += __shfl_down(lsum, off);
    if (lane == 0) wred[wid] = lsum;
    __syncthreads();
    if (tid == 0)
        atomicAdd(loss_acc, (double)wred[0] + (double)wred[1]);
}

// ======================= FALLBACK PATH (R2, proven) =========================

#define F_A_STRIDE 40
#define F_B_STRIDE 68
#define F_TN 64
#define F_CCH 32

__global__ __launch_bounds__(128) void k_norms_fb(const float* __restrict__ cb,
                                                  float* __restrict__ e2,
                                                  double* __restrict__ loss_acc) {
    if (blockIdx.x == 0 && threadIdx.x == 0) *loss_acc = 0.0;
    int k = blockIdx.x * 128 + threadIdx.x;
    e2[k] = np_sum256_sq<1>(cb + (size_t)k * DIM);
}

__global__ __launch_bounds__(128) void k_main_fp32(const float* __restrict__ x,
                                                   const float* __restrict__ cb,
                                                   const float* __restrict__ e2,
                                                   float* __restrict__ out,
                                                   double* __restrict__ loss_acc) {
    __shared__ __align__(16) float Alds[DIM * F_A_STRIDE];
    __shared__ __align__(16) float Bst[F_CCH * F_B_STRIDE];
    __shared__ float As[TM];
    __shared__ int   bidx[TM];
    __shared__ float wred[2];

    const int tid = threadIdx.x;
    const int tx  = tid & 15;
    const int ty  = tid >> 4;

    const int b  = blockIdx.x >> 7;
    const int t0 = (blockIdx.x & 127) * TM;
    const float* xb = x + ((size_t)b * DIM) * NT + t0;

    {
        int u  = tid >> 3;
        int t4 = (tid & 7) * 4;
#pragma unroll
        for (int pass = 0; pass < 16; ++pass) {
            int c = pass * 16 + u;
            float4 v = *(const float4*)(xb + (size_t)c * NT + t4);
            *(float4*)(&Alds[c * F_A_STRIDE + t4]) = v;
        }
    }
    __syncthreads();
    if (tid < TM) As[tid] = np_sum256_sq<F_A_STRIDE>(&Alds[tid]);

    float bestv[4];
    int   besti[4];
#pragma unroll
    for (int i = 0; i < 4; ++i) { bestv[i] = 3.402823466e+38f; besti[i] = 0; }

    const int kk = tid >> 3;
    const int cg = (tid & 7) * 4;

    for (int kt = 0; kt < 16; ++kt) {
        const int k0 = kt * F_TN;
        const float* cbb = cb + (size_t)(k0 + kk) * DIM + cg;
        float4 cn = *(const float4*)(e2 + k0 + tx * 4);
        float4 q0 = *(const float4*)(cbb);
        float4 q1 = *(const float4*)(cbb + 16 * DIM);
        float4 q2 = *(const float4*)(cbb + 32 * DIM);
        float4 q3 = *(const float4*)(cbb + 48 * DIM);

        float acc[4][4];
#pragma unroll
        for (int i = 0; i < 4; ++i)
#pragma unroll
            for (int j = 0; j < 4; ++j) acc[i][j] = 0.f;

        for (int ch = 0; ch < 8; ++ch) {
            __syncthreads();
            {
                float t0v[4] = { q0.x, q0.y, q0.z, q0.w };
                float t1v[4] = { q1.x, q1.y, q1.z, q1.w };
                float t2v[4] = { q2.x, q2.y, q2.z, q2.w };
                float t3v[4] = { q3.x, q3.y, q3.z, q3.w };
#pragma unroll
                for (int i = 0; i < 4; ++i) {
                    Bst[(cg + i) * F_B_STRIDE + kk]      = t0v[i];
                    Bst[(cg + i) * F_B_STRIDE + kk + 16] = t1v[i];
                    Bst[(cg + i) * F_B_STRIDE + kk + 32] = t2v[i];
                    Bst[(cg + i) * F_B_STRIDE + kk + 48] = t3v[i];
                }
            }
            if (ch < 7) {
                const float* p = cbb + (ch + 1) * F_CCH;
                q0 = *(const float4*)(p);
                q1 = *(const float4*)(p + 16 * DIM);
                q2 = *(const float4*)(p + 32 * DIM);
                q3 = *(const float4*)(p + 48 * DIM);
            }
            __syncthreads();

            const float* Ab = &Alds[(ch * F_CCH) * F_A_STRIDE + ty * 4];
#pragma unroll
            for (int c = 0; c < F_CCH; ++c) {
                float4 av = *(const float4*)(Ab + c * F_A_STRIDE);
                float4 bv = *(const float4*)(&Bst[c * F_B_STRIDE + tx * 4]);
                float a4[4] = { av.x, av.y, av.z, av.w };
                float b4[4] = { bv.x, bv.y, bv.z, bv.w };
#pragma unroll
                for (int i = 0; i < 4; ++i)
#pragma unroll
                    for (int j = 0; j < 4; ++j)
                        acc[i][j] = __builtin_fmaf(a4[i], b4[j], acc[i][j]);
            }
        }

        {
            const float* cnp = (const float*)&cn;
            float Arow[4];
#pragma unroll
            for (int i = 0; i < 4; ++i) Arow[i] = As[ty * 4 + i];
#pragma unroll
            for (int j = 0; j < 4; ++j) {
                int kidx = k0 + tx * 4 + j;
                float kn = cnp[j];
#pragma unroll
                for (int i = 0; i < 4; ++i) {
                    float t1 = Arow[i] - 2.0f * acc[i][j];
                    float s  = t1 + kn;
                    if (s < bestv[i]) { bestv[i] = s; besti[i] = kidx; }
                }
            }
        }
    }

#pragma unroll
    for (int i = 0; i < 4; ++i) {
        float v = bestv[i]; int idx = besti[i];
#pragma unroll
        for (int off = 1; off < 16; off <<= 1) {
            float ov = __shfl_xor(v, off);
            int   oi = __shfl_xor(idx, off);
            if (ov < v || (ov == v && oi < idx)) { v = ov; idx = oi; }
        }
        if (tx == 0) bidx[ty * 4 + i] = idx;
    }
    __syncthreads();

    if (tid < TM) out[IDX_OFF + (size_t)blockIdx.x * TM + tid] = (float)bidx[tid];

    float lsum = 0.f;
    {
        int tt = tid & 31;
        int cq = tid >> 5;
        int myidx = bidx[tt];
        const float* myrow = cb + (size_t)myidx * DIM;
        float* oq = out + ((size_t)b * DIM) * NT + t0 + tt;
#pragma unroll 4
        for (int cc = 0; cc < 64; ++cc) {
            int c = cc * 4 + cq;
            float q = myrow[c];
            float d = q - Alds[c * F_A_STRIDE + tt];
            lsum += d * d;
            oq[(size_t)c * NT] = q;
        }
    }
#pragma unroll
    for (int off = 32; off > 0; off >>= 1) lsum += __shfl_down(lsum, off);
    if ((tid & 63) == 0) wred[tid >> 6] = lsum;
    __syncthreads();
    if (tid == 0) atomicAdd(loss_acc, (double)wred[0] + (double)wred[1]);
}

// ---------------- finalize scalar loss --------------------------------------
__global__ void k_final(const double* __restrict__ loss_acc, float* __restrict__ out) {
    out[LOSS_OFF] = (float)(*loss_acc * (1.25 / (double)Q_SIZE));
}

extern "C" void kernel_launch(void* const* d_in, const int* in_sizes, int n_in,
                              void* d_out, int out_size, void* d_ws, size_t ws_size,
                              hipStream_t stream) {
    const float* x  = (const float*)d_in[0];
    const float* cb = (const float*)d_in[1];
    float* out = (float*)d_out;
    double* loss_acc = (double*)d_ws;

    if (ws_size >= (size_t)WS_REQ) {
        float*    e2  = (float*)((char*)d_ws + WS_E2);
        ushort_t* cbf = (ushort_t*)((char*)d_ws + WS_CBF);
        hipLaunchKernelGGL(k_prep, dim3(261), dim3(256), 0, stream, cb, e2, cbf, loss_acc);
        hipLaunchKernelGGL(k_main_mfma, dim3(NROWS / TMQ), dim3(128), 0, stream,
                           x, cb, e2, cbf, out, loss_acc);
    } else {
        float* e2 = (float*)((char*)d_ws + 16);
        hipLaunchKernelGGL(k_norms_fb, dim3(K_CODES / 128), dim3(128), 0, stream,
                           cb, e2, loss_acc);
        hipLaunchKernelGGL(k_main_fp32, dim3(NROWS / TM), dim3(128), 0, stream,
                           x, cb, e2, out, loss_acc);
    }
    hipLaunchKernelGGL(k_final, dim3(1), dim3(1), 0, stream, loss_acc, out);
}

// Round 7
// 285.516 us; speedup vs baseline: 1.1214x; 1.1214x over previous
//
#include <hip/hip_runtime.h>

typedef unsigned int uint;
typedef unsigned short ushort_t;
typedef unsigned long long u64;
typedef __attribute__((ext_vector_type(8))) short bf16x8;
typedef __attribute__((ext_vector_type(4))) float f32x4;

#define K_CODES 1024
#define DIM     256
#define NB      16
#define NT      4096
#define NROWS   65536
#define Q_SIZE  16777216
#define IDX_OFF ((size_t)Q_SIZE)
#define LOSS_OFF ((size_t)(Q_SIZE + NROWS))

#define TM   32
#define AST  32          // Alds stride (words): 128 B rows -> lane-linear DMA staging
#define CAP  1536
#define EPS  6e-3f

// fast-path ws layout: [0] loss double; [4096] e2 f32[1024]; [32768] cbf bf16 512 KB
#define WS_E2   4096
#define WS_CBF  32768
#define WS_REQ  (WS_CBF + K_CODES * DIM * 2)   // 557056

__device__ __forceinline__ ushort_t f2bf(float f) {
    uint u = __builtin_bit_cast(uint, f);
    return (ushort_t)((u + 0x7FFFu + ((u >> 16) & 1u)) >> 16);   // RNE
}

// async global->LDS DMA, 16 B per lane; lds arg must be wave-uniform base
__device__ __forceinline__ void gl2lds16(const void* g, void* l) {
    __builtin_amdgcn_global_load_lds((const __attribute__((address_space(1))) void*)g,
                                     (__attribute__((address_space(3))) void*)l,
                                     16, 0, 0);
}

// issue 8 independent 16-B loads (one B tile) in ONE volatile asm block.
// Registers are asm-owned: the compiler cannot collapse the double-buffer or
// serialize the loads. Completion is claimed by an explicit counted vmcnt.
__device__ __forceinline__ void issue8(bf16x8 (&o)[8], const char* p) {
    const char* q = p + 4096;
    asm volatile(
        "global_load_dwordx4 %0, %8, off\n\t"
        "global_load_dwordx4 %1, %8, off offset:1024\n\t"
        "global_load_dwordx4 %2, %8, off offset:2048\n\t"
        "global_load_dwordx4 %3, %8, off offset:3072\n\t"
        "global_load_dwordx4 %4, %9, off\n\t"
        "global_load_dwordx4 %5, %9, off offset:1024\n\t"
        "global_load_dwordx4 %6, %9, off offset:2048\n\t"
        "global_load_dwordx4 %7, %9, off offset:3072"
        : "=&v"(o[0]), "=&v"(o[1]), "=&v"(o[2]), "=&v"(o[3]),
          "=&v"(o[4]), "=&v"(o[5]), "=&v"(o[6]), "=&v"(o[7])
        : "v"(p), "v"(q));
}

// counted wait + scheduling fence (guide rule #18: fence right after waitcnt)
#define VWAIT(N) do { asm volatile("s_waitcnt vmcnt(" #N ")"); \
                      __builtin_amdgcn_sched_barrier(0); } while (0)

// ---- numpy pairwise_sum(a*a), n=256 (bit-exact, R2-verified) ---------------
template<int S>
__device__ __forceinline__ float np_pw128_sq(const float* __restrict__ a) {
#pragma clang fp contract(off)
    float r[8];
#pragma unroll
    for (int j = 0; j < 8; ++j) { float v = a[j * S]; r[j] = v * v; }
    for (int i = 8; i < 128; i += 8) {
#pragma unroll
        for (int j = 0; j < 8; ++j) { float v = a[(i + j) * S]; r[j] += v * v; }
    }
    return ((r[0] + r[1]) + (r[2] + r[3])) + ((r[4] + r[5]) + (r[6] + r[7]));
}
template<int S>
__device__ __forceinline__ float np_sum256_sq(const float* __restrict__ a) {
#pragma clang fp contract(off)
    float s0 = np_pw128_sq<S>(a);
    float s1 = np_pw128_sq<S>(a + 128 * S);
    return s0 + s1;
}

// ============================ FAST PATH (MFMA) ==============================

// K1: e2 norms + fragment-order bf16 codebook + loss=0
__global__ __launch_bounds__(256) void k_prep(const float* __restrict__ cb,
                                              float* __restrict__ e2,
                                              ushort_t* __restrict__ cbf,
                                              double* __restrict__ loss_acc) {
    int g = blockIdx.x;
    if (g < 256) {            // slot s = (tileN*8+kc)*64+lane; 16 B/slot, 2 threads/slot
        int hs   = g * 256 + threadIdx.x;          // 0..65535
        int s    = hs >> 1, part = hs & 1;
        int lane = s & 63, kc = (s >> 6) & 7, tileN = s >> 9;
        int code = tileN * 16 + (lane & 15);
        int k0   = kc * 32 + (lane >> 4) * 8 + part * 4;
        const float* p = cb + (size_t)code * DIM + k0;
        union { ushort_t u[4]; u64 v; } o;
#pragma unroll
        for (int j = 0; j < 4; ++j) o.u[j] = f2bf(p[j]);
        *(u64*)(cbf + (size_t)s * 8 + part * 4) = o.v;
    } else if (g < 260) {     // np-exact code norms
        int k = (g - 256) * 256 + threadIdx.x;
        e2[k] = np_sum256_sq<1>(cb + (size_t)k * DIM);
    } else {
        if (threadIdx.x == 0) *loss_acc = 0.0;
    }
}

// per-tile screen body: 8 MFMA + score + every-4th-tile checkpoint (R2 semantics)
#define KBODY(SET, IT)                                                         \
    do {                                                                       \
        f32x4 acc = {0.f, 0.f, 0.f, 0.f};                                      \
        _Pragma("unroll")                                                      \
        for (int kc = 0; kc < 8; ++kc)                                         \
            acc = __builtin_amdgcn_mfma_f32_16x16x32_bf16(afrag[kc], SET[kc],  \
                                                          acc, 0, 0, 0);       \
        float e2v = e2s[(half * 32 + (IT)) * 16 + col];                        \
        _Pragma("unroll")                                                      \
        for (int r = 0; r < 4; ++r) sb[((IT) & 3) * 4 + r] = e2v - 2.0f * acc[r]; \
        if ((((IT) & 3) == 3)) {                                               \
            float bm[4];                                                       \
            _Pragma("unroll")                                                  \
            for (int r = 0; r < 4; ++r)                                        \
                bm[r] = fminf(fminf(sb[r], sb[4 + r]), fminf(sb[8 + r], sb[12 + r])); \
            _Pragma("unroll")                                                  \
            for (int mask = 1; mask < 16; mask <<= 1)                          \
                _Pragma("unroll")                                              \
                for (int r = 0; r < 4; ++r)                                    \
                    bm[r] = fminf(bm[r], __shfl_xor(bm[r], mask, 64));         \
            _Pragma("unroll")                                                  \
            for (int r = 0; r < 4; ++r) rowmin[r] = fminf(rowmin[r], bm[r]);   \
            _Pragma("unroll")                                                  \
            for (int tb = 0; tb < 4; ++tb)                                     \
                _Pragma("unroll")                                              \
                for (int r = 0; r < 4; ++r)                                    \
                    if (sb[tb * 4 + r] <= rowmin[r] + EPS) {                   \
                        int code = (half * 32 + ((IT) - 3 + tb)) * 16 + col;   \
                        int rowL = r0 + quad * 4 + r;                          \
                        int pos  = atomicAdd(&cnt, 1);                         \
                        if (pos < CAP) cand[pos] = ((uint)rowL << 10) | (uint)code; \
                    }                                                          \
        }                                                                      \
    } while (0)

// K2: barrier-free half-split K-loop, asm-owned 8-deep pipelined B prefetch.
__global__ __launch_bounds__(256, 3) void k_main_mfma(const float* __restrict__ x,
                                                      const float* __restrict__ cb,
                                                      const float* __restrict__ e2g,
                                                      const ushort_t* __restrict__ cbf,
                                                      float* __restrict__ out,
                                                      double* __restrict__ loss_acc) {
    __shared__ __align__(16) float Alds[DIM * AST];          // 32768 B  x tile [c][t]
    __shared__ float e2s[K_CODES];                           //  4096 B (keeps vmcnt clean)
    __shared__ __align__(16) uint  uni[CAP];                 //  6144 B  cand U AsP
    __shared__ u64   keys[TM];                               //   256 B
    __shared__ float As[TM];                                 //   128 B
    __shared__ float wred[4];
    __shared__ int   cnt;
    // total ~43.4 KiB -> 3 blocks/CU (12 waves), same as measured residency before

    uint* const cand = uni;
    float (* const AsP)[8][2] = (float (*)[8][2])uni;        // [TM][8][2] = 2048 B

    const int tid  = threadIdx.x;
    const int lane = tid & 63;
    const int wid  = tid >> 6;          // 0..3
    const int half = wid & 1;           // code half (tiles 0..31 / 32..63)
    const int r0   = (wid >> 1) * 16;   // row-group base
    const int col  = lane & 15;
    const int quad = lane >> 4;

    const int b  = blockIdx.x >> 7;
    const int t0 = (blockIdx.x & 127) * TM;
    const float* xb = x + (size_t)b * DIM * NT + t0;

    if (tid < TM) keys[tid] = ~0ull;
    if (tid == 0) cnt = 0;

    // stage x tile fp32 [c][t] via global_load_lds (lane-linear with AST=32)
    {
        int c0 = tid >> 3, t4 = (tid & 7) * 4;
#pragma unroll
        for (int pp = 0; pp < 8; ++pp)
            gl2lds16(xb + (size_t)(pp * 32 + c0) * NT + t4, &Alds[1024 * pp + 256 * wid]);
    }
    for (int i = tid; i < K_CODES; i += 256) e2s[i] = e2g[i];
    __syncthreads();

    // np row-norm partials into AsP (aliases cand region; freed before K-loop)
    {
#pragma clang fp contract(off)
        int rw = tid >> 3, j = tid & 7;
        float rlo = 0.f, rhi = 0.f;
        for (int m = 0; m < 16; ++m)  { float v = Alds[(j + 8 * m) * AST + rw];  rlo += v * v; }
        for (int m = 16; m < 32; ++m) { float v = Alds[(j + 8 * m) * AST + rw];  rhi += v * v; }
        AsP[rw][j][0] = rlo; AsP[rw][j][1] = rhi;
    }

    // A fragments: lane holds A[m = r0+col][k = kc*32 + quad*8 + j]
    bf16x8 afrag[8];
#pragma unroll
    for (int kc = 0; kc < 8; ++kc) {
        union { ushort_t u[8]; bf16x8 v; } tmp;
#pragma unroll
        for (int j = 0; j < 8; ++j)
            tmp.u[j] = f2bf(Alds[(kc * 32 + quad * 8 + j) * AST + r0 + col]);
        afrag[kc] = tmp.v;
    }

    __syncthreads();   // AsP complete

    if (tid < TM) {    // np combine lo/hi then lo+hi (bit-exact np_sum256_sq)
        const float* p = &AsP[tid][0][0];
        float lo = ((p[0] + p[2]) + (p[4] + p[6])) + ((p[8] + p[10]) + (p[12] + p[14]));
        float hi = ((p[1] + p[3]) + (p[5] + p[7])) + ((p[9] + p[11]) + (p[13] + p[15]));
        As[tid] = lo + hi;
    }
    __syncthreads();   // As done; uni region now free for cand

    // ---- barrier-free K-loop: asm double-buffer, counted vmcnt(8) ----------
    float rowmin[4] = {3.4e38f, 3.4e38f, 3.4e38f, 3.4e38f};
    float sb[16];
    // tile byte layout: tile T at T*8192 + kc*1024 + lane*16
    const char* pb = (const char*)cbf + (size_t)(half * 32) * 8192 + (size_t)lane * 16;

    bf16x8 bfA[8], bfB[8];
    issue8(bfA, pb);                       // tile 0 in flight (8 outstanding)
#pragma unroll
    for (int it2 = 0; it2 < 16; ++it2) {
        const int itA = it2 * 2, itB = itA + 1;
        issue8(bfB, pb + (size_t)itB * 8192);        // 16 outstanding
        VWAIT(8);                                     // tile itA ready
        KBODY(bfA, itA);
        if (itB < 31) {
            issue8(bfA, pb + (size_t)(itB + 1) * 8192);
            VWAIT(8);                                 // tile itB ready
        } else {
            VWAIT(0);                                 // drain last tile
        }
        KBODY(bfB, itB);
    }
    __syncthreads();   // cand/cnt all ready

    // exact np-chain rescore (identical fmaf order; crow via float4)
    {
        int n = cnt;
        bool over = (n > CAP);
        int total = over ? (TM * K_CODES) : n;
        for (int i = tid; i < total; i += 256) {
            uint pk   = over ? (uint)i : cand[i];
            int row   = pk >> 10;
            int code  = pk & 1023;
            const float4* crow4 = (const float4*)(cb + (size_t)code * DIM);
            float acc = 0.f;
#pragma unroll 4
            for (int c8 = 0; c8 < 32; ++c8) {
                float4 u = crow4[2 * c8];
                float4 v = crow4[2 * c8 + 1];
                int c0 = c8 * 8;
                acc = __builtin_fmaf(Alds[(c0 + 0) * AST + row], u.x, acc);
                acc = __builtin_fmaf(Alds[(c0 + 1) * AST + row], u.y, acc);
                acc = __builtin_fmaf(Alds[(c0 + 2) * AST + row], u.z, acc);
                acc = __builtin_fmaf(Alds[(c0 + 3) * AST + row], u.w, acc);
                acc = __builtin_fmaf(Alds[(c0 + 4) * AST + row], v.x, acc);
                acc = __builtin_fmaf(Alds[(c0 + 5) * AST + row], v.y, acc);
                acc = __builtin_fmaf(Alds[(c0 + 6) * AST + row], v.z, acc);
                acc = __builtin_fmaf(Alds[(c0 + 7) * AST + row], v.w, acc);
            }
            float t1 = As[row] - 2.0f * acc;     // fl(A-2B): 2*acc exact
            float d  = t1 + e2s[code];           // fl(+C), e2s == e2g bitwise
            uint ub  = __builtin_bit_cast(uint, d);
            ub = (ub >> 31) ? ~ub : (ub | 0x80000000u);   // sortable float key
            atomicMin(&keys[row], ((u64)ub << 32) | (u64)(uint)code);
        }
    }
    __syncthreads();

    if (tid < TM) out[IDX_OFF + (size_t)blockIdx.x * TM + tid] =
        (float)(int)(keys[tid] & 1023u);

    // epilogue: gather q (float4), transposed coalesced write, loss partial
    float lsum = 0.f;
    {
        int tt = tid & 31;
        int cq = tid >> 5;     // 0..7 -> channel block [cq*32, cq*32+32)
        int myidx = (int)(keys[tt] & 1023u);
        const float4* myrow4 = (const float4*)(cb + (size_t)myidx * DIM + cq * 32);
        float* oq = out + (size_t)b * DIM * NT + (size_t)(cq * 32) * NT + t0 + tt;
#pragma unroll
        for (int i8 = 0; i8 < 8; ++i8) {
            float4 q4 = myrow4[i8];
            float qv[4] = { q4.x, q4.y, q4.z, q4.w };
#pragma unroll
            for (int u = 0; u < 4; ++u) {
                int c = cq * 32 + i8 * 4 + u;
                float dd = qv[u] - Alds[c * AST + tt];
                lsum += dd * dd;
                oq[(size_t)(i8 * 4 + u) * NT] = qv[u];
            }
        }
    }
#pragma unroll
    for (int off = 32; off > 0; off >>= 1) lsum += __shfl_down(lsum, off);
    if (lane == 0) wred[wid] = lsum;
    __syncthreads();
    if (tid == 0)
        atomicAdd(loss_acc, (double)wred[0] + (double)wred[1] + (double)wred[2] + (double)wred[3]);
}

// ======================= FALLBACK PATH (R2, proven) =========================

#define F_A_STRIDE 40
#define F_B_STRIDE 68
#define F_TN 64
#define F_CCH 32

__global__ __launch_bounds__(128) void k_norms_fb(const float* __restrict__ cb,
                                                  float* __restrict__ e2,
                                                  double* __restrict__ loss_acc) {
    if (blockIdx.x == 0 && threadIdx.x == 0) *loss_acc = 0.0;
    int k = blockIdx.x * 128 + threadIdx.x;
    e2[k] = np_sum256_sq<1>(cb + (size_t)k * DIM);
}

__global__ __launch_bounds__(128) void k_main_fp32(const float* __restrict__ x,
                                                   const float* __restrict__ cb,
                                                   const float* __restrict__ e2,
                                                   float* __restrict__ out,
                                                   double* __restrict__ loss_acc) {
    __shared__ __align__(16) float Alds[DIM * F_A_STRIDE];
    __shared__ __align__(16) float Bst[F_CCH * F_B_STRIDE];
    __shared__ float As[TM];
    __shared__ int   bidx[TM];
    __shared__ float wred[2];

    const int tid = threadIdx.x;
    const int tx  = tid & 15;
    const int ty  = tid >> 4;

    const int b  = blockIdx.x >> 7;
    const int t0 = (blockIdx.x & 127) * TM;
    const float* xb = x + ((size_t)b * DIM) * NT + t0;

    {
        int u  = tid >> 3;
        int t4 = (tid & 7) * 4;
#pragma unroll
        for (int pass = 0; pass < 16; ++pass) {
            int c = pass * 16 + u;
            float4 v = *(const float4*)(xb + (size_t)c * NT + t4);
            *(float4*)(&Alds[c * F_A_STRIDE + t4]) = v;
        }
    }
    __syncthreads();
    if (tid < TM) As[tid] = np_sum256_sq<F_A_STRIDE>(&Alds[tid]);

    float bestv[4];
    int   besti[4];
#pragma unroll
    for (int i = 0; i < 4; ++i) { bestv[i] = 3.402823466e+38f; besti[i] = 0; }

    const int kk = tid >> 3;
    const int cg = (tid & 7) * 4;

    for (int kt = 0; kt < 16; ++kt) {
        const int k0 = kt * F_TN;
        const float* cbb = cb + (size_t)(k0 + kk) * DIM + cg;
        float4 cn = *(const float4*)(e2 + k0 + tx * 4);
        float4 q0 = *(const float4*)(cbb);
        float4 q1 = *(const float4*)(cbb + 16 * DIM);
        float4 q2 = *(const float4*)(cbb + 32 * DIM);
        float4 q3 = *(const float4*)(cbb + 48 * DIM);

        float acc[4][4];
#pragma unroll
        for (int i = 0; i < 4; ++i)
#pragma unroll
            for (int j = 0; j < 4; ++j) acc[i][j] = 0.f;

        for (int ch = 0; ch < 8; ++ch) {
            __syncthreads();
            {
                float t0v[4] = { q0.x, q0.y, q0.z, q0.w };
                float t1v[4] = { q1.x, q1.y, q1.z, q1.w };
                float t2v[4] = { q2.x, q2.y, q2.z, q2.w };
                float t3v[4] = { q3.x, q3.y, q3.z, q3.w };
#pragma unroll
                for (int i = 0; i < 4; ++i) {
                    Bst[(cg + i) * F_B_STRIDE + kk]      = t0v[i];
                    Bst[(cg + i) * F_B_STRIDE + kk + 16] = t1v[i];
                    Bst[(cg + i) * F_B_STRIDE + kk + 32] = t2v[i];
                    Bst[(cg + i) * F_B_STRIDE + kk + 48] = t3v[i];
                }
            }
            if (ch < 7) {
                const float* p = cbb + (ch + 1) * F_CCH;
                q0 = *(const float4*)(p);
                q1 = *(const float4*)(p + 16 * DIM);
                q2 = *(const float4*)(p + 32 * DIM);
                q3 = *(const float4*)(p + 48 * DIM);
            }
            __syncthreads();

            const float* Ab = &Alds[(ch * F_CCH) * F_A_STRIDE + ty * 4];
#pragma unroll
            for (int c = 0; c < F_CCH; ++c) {
                float4 av = *(const float4*)(Ab + c * F_A_STRIDE);
                float4 bv = *(const float4*)(&Bst[c * F_B_STRIDE + tx * 4]);
                float a4[4] = { av.x, av.y, av.z, av.w };
                float b4[4] = { bv.x, bv.y, bv.z, bv.w };
#pragma unroll
                for (int i = 0; i < 4; ++i)
#pragma unroll
                    for (int j = 0; j < 4; ++j)
                        acc[i][j] = __builtin_fmaf(a4[i], b4[j], acc[i][j]);
            }
        }

        {
            const float* cnp = (const float*)&cn;
            float Arow[4];
#pragma unroll
            for (int i = 0; i < 4; ++i) Arow[i] = As[ty * 4 + i];
#pragma unroll
            for (int j = 0; j < 4; ++j) {
                int kidx = k0 + tx * 4 + j;
                float kn = cnp[j];
#pragma unroll
                for (int i = 0; i < 4; ++i) {
                    float t1 = Arow[i] - 2.0f * acc[i][j];
                    float s  = t1 + kn;
                    if (s < bestv[i]) { bestv[i] = s; besti[i] = kidx; }
                }
            }
        }
    }

#pragma unroll
    for (int i = 0; i < 4; ++i) {
        float v = bestv[i]; int idx = besti[i];
#pragma unroll
        for (int off = 1; off < 16; off <<= 1) {
            float ov = __shfl_xor(v, off);
            int   oi = __shfl_xor(idx, off);
            if (ov < v || (ov == v && oi < idx)) { v = ov; idx = oi; }
        }
        if (tx == 0) bidx[ty * 4 + i] = idx;
    }
    __syncthreads();

    if (tid < TM) out[IDX_OFF + (size_t)blockIdx.x * TM + tid] = (float)bidx[tid];

    float lsum = 0.f;
    {
        int tt = tid & 31;
        int cq = tid >> 5;
        int myidx = bidx[tt];
        const float* myrow = cb + (size_t)myidx * DIM;
        float* oq = out + ((size_t)b * DIM) * NT + t0 + tt;
#pragma unroll 4
        for (int cc = 0; cc < 64; ++cc) {
            int c = cc * 4 + cq;
            float q = myrow[c];
            float d = q - Alds[c * F_A_STRIDE + tt];
            lsum += d * d;
            oq[(size_t)c * NT] = q;
        }
    }
#pragma unroll
    for (int off = 32; off > 0; off >>= 1) lsum += __shfl_down(lsum, off);
    if ((tid & 63) == 0) wred[tid >> 6] = lsum;
    __syncthreads();
    if (tid == 0) atomicAdd(loss_acc, (double)wred[0] + (double)wred[1]);
}

// ---------------- finalize scalar loss --------------------------------------
__global__ void k_final(const double* __restrict__ loss_acc, float* __restrict__ out) {
    out[LOSS_OFF] = (float)(*loss_acc * (1.25 / (double)Q_SIZE));
}

extern "C" void kernel_launch(void* const* d_in, const int* in_sizes, int n_in,
                              void* d_out, int out_size, void* d_ws, size_t ws_size,
                              hipStream_t stream) {
    const float* x  = (const float*)d_in[0];
    const float* cb = (const float*)d_in[1];
    float* out = (float*)d_out;
    double* loss_acc = (double*)d_ws;

    if (ws_size >= (size_t)WS_REQ) {
        float*    e2  = (float*)((char*)d_ws + WS_E2);
        ushort_t* cbf = (ushort_t*)((char*)d_ws + WS_CBF);
        hipLaunchKernelGGL(k_prep, dim3(261), dim3(256), 0, stream, cb, e2, cbf, loss_acc);
        hipLaunchKernelGGL(k_main_mfma, dim3(NROWS / TM), dim3(256), 0, stream,
                           x, cb, e2, cbf, out, loss_acc);
    } else {
        float* e2 = (float*)((char*)d_ws + 16);
        hipLaunchKernelGGL(k_norms_fb, dim3(K_CODES / 128), dim3(128), 0, stream,
                           cb, e2, loss_acc);
        hipLaunchKernelGGL(k_main_fp32, dim3(NROWS / TM), dim3(128), 0, stream,
                           x, cb, e2, out, loss_acc);
    }
    hipLaunchKernelGGL(k_final, dim3(1), dim3(1), 0, stream, loss_acc, out);
}

// Round 9
// 281.444 us; speedup vs baseline: 1.1377x; 1.0145x over previous
//
#include <hip/hip_runtime.h>

typedef unsigned int uint;
typedef unsigned short ushort_t;
typedef unsigned long long u64;
typedef __attribute__((ext_vector_type(8))) short bf16x8;
typedef __attribute__((ext_vector_type(4))) float f32x4;

#define K_CODES 1024
#define DIM     256
#define NB      16
#define NT      4096
#define NROWS   65536
#define Q_SIZE  16777216
#define IDX_OFF ((size_t)Q_SIZE)
#define LOSS_OFF ((size_t)(Q_SIZE + NROWS))

#define TM   32
#define AST  32          // Alds stride (words): 128 B rows -> lane-linear DMA staging
#define CAP  1536
#define EPS  6e-3f
#define EPS2 1.2e-2f     // pass-2 collection slack: 2x the proven binding margin

// fast-path ws layout: [0] loss double; [4096] e2 f32[1024]; [32768] cbf bf16 512 KB
#define WS_E2   4096
#define WS_CBF  32768
#define WS_REQ  (WS_CBF + K_CODES * DIM * 2)   // 557056

__device__ __forceinline__ ushort_t f2bf(float f) {
    uint u = __builtin_bit_cast(uint, f);
    return (ushort_t)((u + 0x7FFFu + ((u >> 16) & 1u)) >> 16);   // RNE
}

// async global->LDS DMA, 16 B per lane; lds arg must be wave-uniform base
__device__ __forceinline__ void gl2lds16(const void* g, void* l) {
    __builtin_amdgcn_global_load_lds((const __attribute__((address_space(1))) void*)g,
                                     (__attribute__((address_space(3))) void*)l,
                                     16, 0, 0);
}

// ---- numpy pairwise_sum(a*a), n=256 (bit-exact, R2-verified) ---------------
template<int S>
__device__ __forceinline__ float np_pw128_sq(const float* __restrict__ a) {
#pragma clang fp contract(off)
    float r[8];
#pragma unroll
    for (int j = 0; j < 8; ++j) { float v = a[j * S]; r[j] = v * v; }
    for (int i = 8; i < 128; i += 8) {
#pragma unroll
        for (int j = 0; j < 8; ++j) { float v = a[(i + j) * S]; r[j] += v * v; }
    }
    return ((r[0] + r[1]) + (r[2] + r[3])) + ((r[4] + r[5]) + (r[6] + r[7]));
}
template<int S>
__device__ __forceinline__ float np_sum256_sq(const float* __restrict__ a) {
#pragma clang fp contract(off)
    float s0 = np_pw128_sq<S>(a);
    float s1 = np_pw128_sq<S>(a + 128 * S);
    return s0 + s1;
}

// ============================ FAST PATH (MFMA) ==============================

// K1: e2 norms + fragment-order bf16 codebook + loss=0  (R7-proven)
__global__ __launch_bounds__(256) void k_prep(const float* __restrict__ cb,
                                              float* __restrict__ e2,
                                              ushort_t* __restrict__ cbf,
                                              double* __restrict__ loss_acc) {
    int g = blockIdx.x;
    if (g < 256) {            // slot s = (tileN*8+kc)*64+lane; 16 B/slot, 2 threads/slot
        int hs   = g * 256 + threadIdx.x;          // 0..65535
        int s    = hs >> 1, part = hs & 1;
        int lane = s & 63, kc = (s >> 6) & 7, tileN = s >> 9;
        int code = tileN * 16 + (lane & 15);
        int k0   = kc * 32 + (lane >> 4) * 8 + part * 4;
        const float* p = cb + (size_t)code * DIM + k0;
        union { ushort_t u[4]; u64 v; } o;
#pragma unroll
        for (int j = 0; j < 4; ++j) o.u[j] = f2bf(p[j]);
        *(u64*)(cbf + (size_t)s * 8 + part * 4) = o.v;
    } else if (g < 260) {     // np-exact code norms
        int k = (g - 256) * 256 + threadIdx.x;
        e2[k] = np_sum256_sq<1>(cb + (size_t)k * DIM);
    } else {
        if (threadIdx.x == 0) *loss_acc = 0.0;
    }
}

// K2: two-pass screen. Pass 1: quarter-split MFMA, per-lane row minima only
// (no shuffles/atomics in the loop). One butterfly + LDS reduce -> GLOBAL
// per-row bf16 minima. Pass 2: recompute identical scores, collect codes
// within gmin+EPS2 (tiny candidate set). Exact np rescore resolves argmin.
__global__ __launch_bounds__(256, 3) void k_main_mfma(const float* __restrict__ x,
                                                      const float* __restrict__ cb,
                                                      const float* __restrict__ e2g,
                                                      const ushort_t* __restrict__ cbf,
                                                      float* __restrict__ out,
                                                      double* __restrict__ loss_acc) {
    __shared__ __align__(16) float Alds[DIM * AST];          // 32768 B  x tile [c][t]
    __shared__ float e2s[K_CODES];                           //  4096 B
    __shared__ __align__(16) uint  uni[CAP];                 //  6144 B  cand U AsP
    __shared__ float gmW[4][TM];                             //   512 B  per-wave row minima
    __shared__ u64   keys[TM];                               //   256 B
    __shared__ float As[TM];                                 //   128 B
    __shared__ float wred[4];
    __shared__ int   cnt;
    // total ~44 KiB -> 3 blocks/CU

    uint* const cand = uni;
    float (* const AsP)[8][2] = (float (*)[8][2])uni;        // [TM][8][2] = 2048 B

    const int tid  = threadIdx.x;
    const int lane = tid & 63;
    const int wid  = tid >> 6;          // 0..3 -> code-tile quarter
    const int col  = lane & 15;
    const int quad = lane >> 4;

    const int b  = blockIdx.x >> 7;
    const int t0 = (blockIdx.x & 127) * TM;
    const float* xb = x + (size_t)b * DIM * NT + t0;

    if (tid < TM) keys[tid] = ~0ull;
    if (tid == 0) cnt = 0;

    // stage x tile fp32 [c][t] via global_load_lds (lane-linear with AST=32)
    {
        int c0 = tid >> 3, t4 = (tid & 7) * 4;
#pragma unroll
        for (int pp = 0; pp < 8; ++pp)
            gl2lds16(xb + (size_t)(pp * 32 + c0) * NT + t4, &Alds[1024 * pp + 256 * wid]);
    }
    for (int i = tid; i < K_CODES; i += 256) e2s[i] = e2g[i];
    __syncthreads();

    // np row-norm partials into AsP (aliases cand region; freed before pass 2)
    {
#pragma clang fp contract(off)
        int rw = tid >> 3, j = tid & 7;
        float rlo = 0.f, rhi = 0.f;
        for (int m = 0; m < 16; ++m)  { float v = Alds[(j + 8 * m) * AST + rw];  rlo += v * v; }
        for (int m = 16; m < 32; ++m) { float v = Alds[(j + 8 * m) * AST + rw];  rhi += v * v; }
        AsP[rw][j][0] = rlo; AsP[rw][j][1] = rhi;
    }

    // A fragments, BOTH row-groups (R4-proven): lane holds A[g*16+col][kc*32+quad*8+j]
    bf16x8 af[2][8];
#pragma unroll
    for (int g = 0; g < 2; ++g)
#pragma unroll
        for (int kc = 0; kc < 8; ++kc) {
            union { ushort_t u[8]; bf16x8 v; } tmp;
#pragma unroll
            for (int j = 0; j < 8; ++j)
                tmp.u[j] = f2bf(Alds[(kc * 32 + quad * 8 + j) * AST + g * 16 + col]);
            af[g][kc] = tmp.v;
        }

    __syncthreads();   // AsP complete

    if (tid < TM) {    // np combine lo/hi then lo+hi (bit-exact np_sum256_sq)
        const float* p = &AsP[tid][0][0];
        float lo = ((p[0] + p[2]) + (p[4] + p[6])) + ((p[8] + p[10]) + (p[12] + p[14]));
        float hi = ((p[1] + p[3]) + (p[5] + p[7])) + ((p[9] + p[11]) + (p[13] + p[15]));
        As[tid] = lo + hi;
    }
    __syncthreads();   // As done; uni region now free for cand

    // B pointer (R4-proven expressions): wave wid scans tiles [wid*16, wid*16+16)
    const bf16x8* bp = (const bf16x8*)cbf + (size_t)(wid * 16) * 8 * 64 + lane;

    // ---- pass 1: per-lane minima (lean: loads + MFMA + fmin only) ----------
    float pm[2][4] = {{3.4e38f, 3.4e38f, 3.4e38f, 3.4e38f},
                      {3.4e38f, 3.4e38f, 3.4e38f, 3.4e38f}};
#pragma unroll 2
    for (int t = 0; t < 16; ++t) {
        bf16x8 bf[8];
#pragma unroll
        for (int kc = 0; kc < 8; ++kc) bf[kc] = bp[(t * 8 + kc) * 64];
        f32x4 acc0 = {0.f, 0.f, 0.f, 0.f};
        f32x4 acc1 = {0.f, 0.f, 0.f, 0.f};
#pragma unroll
        for (int kc = 0; kc < 8; ++kc) {
            acc0 = __builtin_amdgcn_mfma_f32_16x16x32_bf16(af[0][kc], bf[kc], acc0, 0, 0, 0);
            acc1 = __builtin_amdgcn_mfma_f32_16x16x32_bf16(af[1][kc], bf[kc], acc1, 0, 0, 0);
        }
        float e2v = e2s[(wid * 16 + t) * 16 + col];
#pragma unroll
        for (int r = 0; r < 4; ++r) {
            pm[0][r] = fminf(pm[0][r], e2v - 2.0f * acc0[r]);
            pm[1][r] = fminf(pm[1][r], e2v - 2.0f * acc1[r]);
        }
    }
    // reduce across the 16 cols of this quad (once, not per checkpoint)
#pragma unroll
    for (int mask = 1; mask < 16; mask <<= 1)
#pragma unroll
        for (int g = 0; g < 2; ++g)
#pragma unroll
            for (int r = 0; r < 4; ++r)
                pm[g][r] = fminf(pm[g][r], __shfl_xor(pm[g][r], mask, 64));
    // publish this wave's per-row minima; then reduce across waves
    if (col == 0) {
#pragma unroll
        for (int g = 0; g < 2; ++g)
#pragma unroll
            for (int r = 0; r < 4; ++r)
                gmW[wid][g * 16 + quad * 4 + r] = pm[g][r];
    }
    __syncthreads();
    float gmin[2][4];
#pragma unroll
    for (int g = 0; g < 2; ++g)
#pragma unroll
        for (int r = 0; r < 4; ++r) {
            int row = g * 16 + quad * 4 + r;
            gmin[g][r] = fminf(fminf(gmW[0][row], gmW[1][row]),
                               fminf(gmW[2][row], gmW[3][row]));
        }

    // ---- pass 2: recompute identical scores, collect vs global min ---------
#pragma unroll 2
    for (int t = 0; t < 16; ++t) {
        bf16x8 bf[8];
#pragma unroll
        for (int kc = 0; kc < 8; ++kc) bf[kc] = bp[(t * 8 + kc) * 64];
        f32x4 acc0 = {0.f, 0.f, 0.f, 0.f};
        f32x4 acc1 = {0.f, 0.f, 0.f, 0.f};
#pragma unroll
        for (int kc = 0; kc < 8; ++kc) {
            acc0 = __builtin_amdgcn_mfma_f32_16x16x32_bf16(af[0][kc], bf[kc], acc0, 0, 0, 0);
            acc1 = __builtin_amdgcn_mfma_f32_16x16x32_bf16(af[1][kc], bf[kc], acc1, 0, 0, 0);
        }
        float e2v = e2s[(wid * 16 + t) * 16 + col];
        int code = (wid * 16 + t) * 16 + col;
#pragma unroll
        for (int r = 0; r < 4; ++r) {
            float s0 = e2v - 2.0f * acc0[r];
            if (s0 <= gmin[0][r] + EPS2) {
                int pos = atomicAdd(&cnt, 1);
                if (pos < CAP) cand[pos] = ((uint)(quad * 4 + r) << 10) | (uint)code;
            }
            float s1 = e2v - 2.0f * acc1[r];
            if (s1 <= gmin[1][r] + EPS2) {
                int pos = atomicAdd(&cnt, 1);
                if (pos < CAP) cand[pos] = ((uint)(16 + quad * 4 + r) << 10) | (uint)code;
            }
        }
    }
    __syncthreads();   // cand/cnt all ready

    // exact np-chain rescore (identical fmaf order; crow via float4) ---------
    {
        int n = cnt;
        bool over = (n > CAP);
        int total = over ? (TM * K_CODES) : n;
        for (int i = tid; i < total; i += 256) {
            uint pk   = over ? (uint)i : cand[i];
            int row   = pk >> 10;
            int code  = pk & 1023;
            const float4* crow4 = (const float4*)(cb + (size_t)code * DIM);
            float acc = 0.f;
#pragma unroll 4
            for (int c8 = 0; c8 < 32; ++c8) {
                float4 u = crow4[2 * c8];
                float4 v = crow4[2 * c8 + 1];
                int c0 = c8 * 8;
                acc = __builtin_fmaf(Alds[(c0 + 0) * AST + row], u.x, acc);
                acc = __builtin_fmaf(Alds[(c0 + 1) * AST + row], u.y, acc);
                acc = __builtin_fmaf(Alds[(c0 + 2) * AST + row], u.z, acc);
                acc = __builtin_fmaf(Alds[(c0 + 3) * AST + row], u.w, acc);
                acc = __builtin_fmaf(Alds[(c0 + 4) * AST + row], v.x, acc);
                acc = __builtin_fmaf(Alds[(c0 + 5) * AST + row], v.y, acc);
                acc = __builtin_fmaf(Alds[(c0 + 6) * AST + row], v.z, acc);
                acc = __builtin_fmaf(Alds[(c0 + 7) * AST + row], v.w, acc);
            }
            float t1 = As[row] - 2.0f * acc;     // fl(A-2B): 2*acc exact
            float d  = t1 + e2s[code];           // fl(+C), e2s == e2g bitwise
            uint ub  = __builtin_bit_cast(uint, d);
            ub = (ub >> 31) ? ~ub : (ub | 0x80000000u);   // sortable float key
            atomicMin(&keys[row], ((u64)ub << 32) | (u64)(uint)code);
        }
    }
    __syncthreads();

    if (tid < TM) out[IDX_OFF + (size_t)blockIdx.x * TM + tid] =
        (float)(int)(keys[tid] & 1023u);

    // epilogue: gather q (float4), transposed coalesced write, loss partial
    float lsum = 0.f;
    {
        int tt = tid & 31;
        int cq = tid >> 5;     // 0..7 -> channel block [cq*32, cq*32+32)
        int myidx = (int)(keys[tt] & 1023u);
        const float4* myrow4 = (const float4*)(cb + (size_t)myidx * DIM + cq * 32);
        float* oq = out + (size_t)b * DIM * NT + (size_t)(cq * 32) * NT + t0 + tt;
#pragma unroll
        for (int i8 = 0; i8 < 8; ++i8) {
            float4 q4 = myrow4[i8];
            float qv[4] = { q4.x, q4.y, q4.z, q4.w };
#pragma unroll
            for (int u = 0; u < 4; ++u) {
                int c = cq * 32 + i8 * 4 + u;
                float dd = qv[u] - Alds[c * AST + tt];
                lsum += dd * dd;
                oq[(size_t)(i8 * 4 + u) * NT] = qv[u];
            }
        }
    }
#pragma unroll
    for (int off = 32; off > 0; off >>= 1) lsum += __shfl_down(lsum, off);
    if (lane == 0) wred[wid] = lsum;
    __syncthreads();
    if (tid == 0)
        atomicAdd(loss_acc, (double)wred[0] + (double)wred[1] + (double)wred[2] + (double)wred[3]);
}

// ======================= FALLBACK PATH (R2, proven) =========================

#define F_A_STRIDE 40
#define F_B_STRIDE 68
#define F_TN 64
#define F_CCH 32

__global__ __launch_bounds__(128) void k_norms_fb(const float* __restrict__ cb,
                                                  float* __restrict__ e2,
                                                  double* __restrict__ loss_acc) {
    if (blockIdx.x == 0 && threadIdx.x == 0) *loss_acc = 0.0;
    int k = blockIdx.x * 128 + threadIdx.x;
    e2[k] = np_sum256_sq<1>(cb + (size_t)k * DIM);
}

__global__ __launch_bounds__(128) void k_main_fp32(const float* __restrict__ x,
                                                   const float* __restrict__ cb,
                                                   const float* __restrict__ e2,
                                                   float* __restrict__ out,
                                                   double* __restrict__ loss_acc) {
    __shared__ __align__(16) float Alds[DIM * F_A_STRIDE];
    __shared__ __align__(16) float Bst[F_CCH * F_B_STRIDE];
    __shared__ float As[TM];
    __shared__ int   bidx[TM];
    __shared__ float wred[2];

    const int tid = threadIdx.x;
    const int tx  = tid & 15;
    const int ty  = tid >> 4;

    const int b  = blockIdx.x >> 7;
    const int t0 = (blockIdx.x & 127) * TM;
    const float* xb = x + ((size_t)b * DIM) * NT + t0;

    {
        int u  = tid >> 3;
        int t4 = (tid & 7) * 4;
#pragma unroll
        for (int pass = 0; pass < 16; ++pass) {
            int c = pass * 16 + u;
            float4 v = *(const float4*)(xb + (size_t)c * NT + t4);
            *(float4*)(&Alds[c * F_A_STRIDE + t4]) = v;
        }
    }
    __syncthreads();
    if (tid < TM) As[tid] = np_sum256_sq<F_A_STRIDE>(&Alds[tid]);

    float bestv[4];
    int   besti[4];
#pragma unroll
    for (int i = 0; i < 4; ++i) { bestv[i] = 3.402823466e+38f; besti[i] = 0; }

    const int kk = tid >> 3;
    const int cg = (tid & 7) * 4;

    for (int kt = 0; kt < 16; ++kt) {
        const int k0 = kt * F_TN;
        const float* cbb = cb + (size_t)(k0 + kk) * DIM + cg;
        float4 cn = *(const float4*)(e2 + k0 + tx * 4);
        float4 q0 = *(const float4*)(cbb);
        float4 q1 = *(const float4*)(cbb + 16 * DIM);
        float4 q2 = *(const float4*)(cbb + 32 * DIM);
        float4 q3 = *(const float4*)(cbb + 48 * DIM);

        float acc[4][4];
#pragma unroll
        for (int i = 0; i < 4; ++i)
#pragma unroll
            for (int j = 0; j < 4; ++j) acc[i][j] = 0.f;

        for (int ch = 0; ch < 8; ++ch) {
            __syncthreads();
            {
                float t0v[4] = { q0.x, q0.y, q0.z, q0.w };
                float t1v[4] = { q1.x, q1.y, q1.z, q1.w };
                float t2v[4] = { q2.x, q2.y, q2.z, q2.w };
                float t3v[4] = { q3.x, q3.y, q3.z, q3.w };
#pragma unroll
                for (int i = 0; i < 4; ++i) {
                    Bst[(cg + i) * F_B_STRIDE + kk]      = t0v[i];
                    Bst[(cg + i) * F_B_STRIDE + kk + 16] = t1v[i];
                    Bst[(cg + i) * F_B_STRIDE + kk + 32] = t2v[i];
                    Bst[(cg + i) * F_B_STRIDE + kk + 48] = t3v[i];
                }
            }
            if (ch < 7) {
                const float* p = cbb + (ch + 1) * F_CCH;
                q0 = *(const float4*)(p);
                q1 = *(const float4*)(p + 16 * DIM);
                q2 = *(const float4*)(p + 32 * DIM);
                q3 = *(const float4*)(p + 48 * DIM);
            }
            __syncthreads();

            const float* Ab = &Alds[(ch * F_CCH) * F_A_STRIDE + ty * 4];
#pragma unroll
            for (int c = 0; c < F_CCH; ++c) {
                float4 av = *(const float4*)(Ab + c * F_A_STRIDE);
                float4 bv = *(const float4*)(&Bst[c * F_B_STRIDE + tx * 4]);
                float a4[4] = { av.x, av.y, av.z, av.w };
                float b4[4] = { bv.x, bv.y, bv.z, bv.w };
#pragma unroll
                for (int i = 0; i < 4; ++i)
#pragma unroll
                    for (int j = 0; j < 4; ++j)
                        acc[i][j] = __builtin_fmaf(a4[i], b4[j], acc[i][j]);
            }
        }

        {
            const float* cnp = (const float*)&cn;
            float Arow[4];
#pragma unroll
            for (int i = 0; i < 4; ++i) Arow[i] = As[ty * 4 + i];
#pragma unroll
            for (int j = 0; j < 4; ++j) {
                int kidx = k0 + tx * 4 + j;
                float kn = cnp[j];
#pragma unroll
                for (int i = 0; i < 4; ++i) {
                    float t1 = Arow[i] - 2.0f * acc[i][j];
                    float s  = t1 + kn;
                    if (s < bestv[i]) { bestv[i] = s; besti[i] = kidx; }
                }
            }
        }
    }

#pragma unroll
    for (int i = 0; i < 4; ++i) {
        float v = bestv[i]; int idx = besti[i];
#pragma unroll
        for (int off = 1; off < 16; off <<= 1) {
            float ov = __shfl_xor(v, off);
            int   oi = __shfl_xor(idx, off);
            if (ov < v || (ov == v && oi < idx)) { v = ov; idx = oi; }
        }
        if (tx == 0) bidx[ty * 4 + i] = idx;
    }
    __syncthreads();

    if (tid < TM) out[IDX_OFF + (size_t)blockIdx.x * TM + tid] = (float)bidx[tid];

    float lsum = 0.f;
    {
        int tt = tid & 31;
        int cq = tid >> 5;
        int myidx = bidx[tt];
        const float* myrow = cb + (size_t)myidx * DIM;
        float* oq = out + ((size_t)b * DIM) * NT + t0 + tt;
#pragma unroll 4
        for (int cc = 0; cc < 64; ++cc) {
            int c = cc * 4 + cq;
            float q = myrow[c];
            float d = q - Alds[c * F_A_STRIDE + tt];
            lsum += d * d;
            oq[(size_t)c * NT] = q;
        }
    }
#pragma unroll
    for (int off = 32; off > 0; off >>= 1) lsum += __shfl_down(lsum, off);
    if ((tid & 63) == 0) wred[tid >> 6] = lsum;
    __syncthreads();
    if (tid == 0) atomicAdd(loss_acc, (double)wred[0] + (double)wred[1]);
}

// ---------------- finalize scalar loss --------------------------------------
__global__ void k_final(const double* __restrict__ loss_acc, float* __restrict__ out) {
    out[LOSS_OFF] = (float)(*loss_acc * (1.25 / (double)Q_SIZE));
}

extern "C" void kernel_launch(void* const* d_in, const int* in_sizes, int n_in,
                              void* d_out, int out_size, void* d_ws, size_t ws_size,
                              hipStream_t stream) {
    const float* x  = (const float*)d_in[0];
    const float* cb = (const float*)d_in[1];
    float* out = (float*)d_out;
    double* loss_acc = (double*)d_ws;

    if (ws_size >= (size_t)WS_REQ) {
        float*    e2  = (float*)((char*)d_ws + WS_E2);
        ushort_t* cbf = (ushort_t*)((char*)d_ws + WS_CBF);
        hipLaunchKernelGGL(k_prep, dim3(261), dim3(256), 0, stream, cb, e2, cbf, loss_acc);
        hipLaunchKernelGGL(k_main_mfma, dim3(NROWS / TM), dim3(256), 0, stream,
                           x, cb, e2, cbf, out, loss_acc);
    } else {
        float* e2 = (float*)((char*)d_ws + 16);
        hipLaunchKernelGGL(k_norms_fb, dim3(K_CODES / 128), dim3(128), 0, stream,
                           cb, e2, loss_acc);
        hipLaunchKernelGGL(k_main_fp32, dim3(NROWS / TM), dim3(128), 0, stream,
                           x, cb, e2, out, loss_acc);
    }
    hipLaunchKernelGGL(k_final, dim3(1), dim3(1), 0, stream, loss_acc, out);
}